// Round 7
// baseline (9728.997 us; speedup 1.0000x reference)
//
#include <hip/hip_runtime.h>
#include <hip/hip_bf16.h>

#define B_ 32
#define S_ 512
#define V_ 8000
#define I_ 256
#define H_ 512
#define LN_EPS 1e-5f
#define NSL 16          // j/k-slices of 32
#define NBP 8           // row-groups of 4 rows
#define NBLK 128
#define PHALF (NBLK * 2048)            // one p buffer: 262144 floats
#define SENT 0xFFFFFFFFFFFFFFFFull     // NaN|NaN pair (memset 0xFF)

// dynamic-LDS float offsets (total 37284 floats = 149136 B)
#define OFF_WR   0      // [32][516] W_rec slice, j-row k-contig
#define OFF_WT   16512  // [32][516] W_tr^T slice: WtS[kl][j] = W_tr[j][g*32+kl]
#define OFF_HB   33024  // [4][516]  h_prev rows (full H per row)
#define OFF_HTS  35088  // [4][33]   phase-A output h_t (own slice)
#define OFF_RED  35220  // [16][4][32] phase-A k-chunk partials
#define OFF_RED2 37268  // float2[8] LN wave partials
#define LDSF     37284

static __device__ __forceinline__ unsigned short f2bf(float x) {
    __hip_bfloat16 h = __float2bfloat16(x);
    return *reinterpret_cast<unsigned short*>(&h);
}

// ---------------- transpose (W_in only) ----------------
__global__ void k_transpose(const float* __restrict__ in, float* __restrict__ out,
                            int R, int C) {
    __shared__ float tile[32][33];
    int c0 = blockIdx.x * 32, r0 = blockIdx.y * 32;
    int tx = threadIdx.x, ty = threadIdx.y;  // block (32,8)
#pragma unroll
    for (int i = 0; i < 32; i += 8)
        tile[ty + i][tx] = in[(size_t)(r0 + ty + i) * C + (c0 + tx)];
    __syncthreads();
#pragma unroll
    for (int i = 0; i < 32; i += 8)
        out[(size_t)(c0 + ty + i) * R + (r0 + tx)] = tile[tx][ty + i];
}

// ---------------- fp32 -> bf16 convert (W_out) ----------------
__global__ __launch_bounds__(256) void k_cvt_bf16(const float* __restrict__ in,
                                                  unsigned short* __restrict__ out, int n4) {
    for (int i = blockIdx.x * 256 + threadIdx.x; i < n4; i += gridDim.x * 256) {
        float4 v = ((const float4*)in)[i];
        ushort4 o;
        o.x = f2bf(v.x); o.y = f2bf(v.y); o.z = f2bf(v.z); o.w = f2bf(v.w);
        ((ushort4*)out)[i] = o;
    }
}

// ---------------- embed gather + input projection: Xp[m][j], m = s*B+b ----------------
__global__ __launch_bounds__(512) void k_embed_proj(
        const int* __restrict__ x_idx, const float* __restrict__ emb,
        const float* __restrict__ WinT, const float* __restrict__ b_in,
        float* __restrict__ Xp) {
    __shared__ float e[8][I_];
    const int m0 = blockIdx.x * 8;
    const int t = threadIdx.x;
    {
        int r = t >> 6, i4 = (t & 63) * 4;
        int m = m0 + r;
        int s = m >> 5, b = m & 31;
        int idx = x_idx[b * S_ + s];
        *(float4*)&e[r][i4] = *(const float4*)&emb[(size_t)idx * I_ + i4];
    }
    __syncthreads();
    const int j = t;
    float acc[8];
    const float bj = b_in[j];
#pragma unroll
    for (int r = 0; r < 8; ++r) acc[r] = bj;
    for (int i = 0; i < I_; ++i) {
        float w = WinT[(size_t)i * H_ + j];
#pragma unroll
        for (int r = 0; r < 8; ++r) acc[r] += e[r][i] * w;
    }
#pragma unroll
    for (int r = 0; r < 8; ++r)
        Xp[(size_t)(m0 + r) * H_ + j] = acc[r];
}

// ---------------- flagless sentinel-poll distributed scan ----------------
// 128 blocks x 512 thr; bid = bp*16 + g. Block (g,bp): j/k-slice g, rows bp*4..+3.
// Per step: phase A (h_t own slice) -> phase B (k-slice-g partial of trunk, all j)
// -> publish 8KB (relaxed stores) -> POLL 15 producers' DATA until != sentinel
// (no flags, no barrier) -> fixed-order sum -> tanh+LN redundant -> h_new in LDS.
// 3 rotating buffers; own region of buffer (s+2)%3 re-sentineled after consuming
// step s (safe: observing all step-s publishes proves all step-(s-1) reads done,
// because each block's publish follows an s_barrier that drains its vmcnt).
__global__ __launch_bounds__(512, 2) void k_scan_poll(
        const float* __restrict__ Xp,
        const float* __restrict__ W_rec, const float* __restrict__ b_rec,
        const float* __restrict__ W_tr,  const float* __restrict__ b_tr,
        const float* __restrict__ gamma, const float* __restrict__ beta,
        float* __restrict__ pP, unsigned short* __restrict__ hsB) {
    extern __shared__ float sm[];
    float*  WrS  = sm + OFF_WR;
    float*  WtS  = sm + OFF_WT;
    float*  hb   = sm + OFF_HB;
    float*  hts  = sm + OFF_HTS;
    float*  red  = sm + OFF_RED;
    float2* red2 = (float2*)(sm + OFF_RED2);

    const int bid = blockIdx.x;
    const int bp = bid >> 4, g = bid & 15;
    const int t = threadIdx.x;
    const int j = t & 31, kc = t >> 5;            // phase-A role
    const int rB = t >> 7, jB = (t & 127) << 2;   // phase-B / LN role
    const int wid = t >> 6;
    const size_t roff64 = (size_t)(rB * 512 + jB) >> 1;  // u64 offset within a producer region

    // stage weight slices into LDS once
    for (int idx = t; idx < 32 * 512; idx += 512) {
        int jj = idx >> 9, k = idx & 511;
        WrS[jj * 516 + k] = W_rec[(size_t)(g * 32 + jj) * H_ + k];
    }
    for (int idx = t; idx < 512 * 32; idx += 512) {
        int jj = idx >> 5, kl = idx & 31;
        WtS[kl * 516 + jj] = W_tr[(size_t)jj * H_ + g * 32 + kl];
    }
    const float brj = b_rec[g * 32 + j];
    const float4 bt4 = *(const float4*)&b_tr[jB];
    const float4 gm4 = *(const float4*)&gamma[jB];
    const float4 be4 = *(const float4*)&beta[jB];
    __syncthreads();

    for (int s = 0; s < S_; ++s) {
        // Xp prefetch for reduce role
        float xv = 0.f;
        if (t < 128) xv = Xp[((size_t)s * B_ + bp * 4 + (t >> 5)) * H_ + g * 32 + (t & 31)];

        // ---- phase A partials: (kc,j) over 32 k for 4 rows ----
        {
            float a0 = 0, a1 = 0, a2 = 0, a3 = 0;
            if (s > 0) {
                const int kbase = kc * 32;
#pragma unroll
                for (int i = 0; i < 8; ++i) {
                    const int k4 = kbase + i * 4;
                    const float4 w4 = *(const float4*)&WrS[j * 516 + k4];
                    const float4 h0 = *(const float4*)&hb[0 * 516 + k4];
                    const float4 h1 = *(const float4*)&hb[1 * 516 + k4];
                    const float4 h2 = *(const float4*)&hb[2 * 516 + k4];
                    const float4 h3 = *(const float4*)&hb[3 * 516 + k4];
                    a0 += h0.x * w4.x + h0.y * w4.y + h0.z * w4.z + h0.w * w4.w;
                    a1 += h1.x * w4.x + h1.y * w4.y + h1.z * w4.z + h1.w * w4.w;
                    a2 += h2.x * w4.x + h2.y * w4.y + h2.z * w4.z + h2.w * w4.w;
                    a3 += h3.x * w4.x + h3.y * w4.y + h3.z * w4.z + h3.w * w4.w;
                }
            }
            red[kc * 128 + 0 * 32 + j] = a0;
            red[kc * 128 + 1 * 32 + j] = a1;
            red[kc * 128 + 2 * 32 + j] = a2;
            red[kc * 128 + 3 * 32 + j] = a3;
        }
        __syncthreads();
        if (t < 128) {
            const int r2 = t >> 5, j2 = t & 31;
            float sum = 0.f;
#pragma unroll
            for (int c = 0; c < 16; ++c) sum += red[c * 128 + r2 * 32 + j2];
            hts[r2 * 33 + j2] = tanhf(sum + xv + brj);
        }
        __syncthreads();

        // ---- phase B: k-slice-g partial of trunk GEMV for ALL j ----
        float4 pa = {0.f, 0.f, 0.f, 0.f};
        {
            const float* hrow = hts + rB * 33;
#pragma unroll 8
            for (int kl = 0; kl < 32; ++kl) {
                const float hv = hrow[kl];
                const float4 w4 = *(const float4*)&WtS[kl * 516 + jB];
                pa.x += hv * w4.x; pa.y += hv * w4.y;
                pa.z += hv * w4.z; pa.w += hv * w4.w;
            }
        }
        union { float2 f; unsigned long long u; } q0, q1;
        q0.f = make_float2(pa.x, pa.y);
        q1.f = make_float2(pa.z, pa.w);
        unsigned long long* pw =
            (unsigned long long*)(pP + (size_t)(s % 3) * PHALF);
        {
            const size_t myb = (size_t)(bp * 16 + g) * 1024 + roff64;
            __hip_atomic_store(&pw[myb], q0.u, __ATOMIC_RELAXED, __HIP_MEMORY_SCOPE_AGENT);
            __hip_atomic_store(&pw[myb + 1], q1.u, __ATOMIC_RELAXED, __HIP_MEMORY_SCOPE_AGENT);
        }

        // ---- consume: poll 15 producers' data directly (no flags) ----
        unsigned long long va[16], vb[16];
        va[g] = q0.u; vb[g] = q1.u;
#pragma unroll
        for (int gg = 0; gg < 16; ++gg) {
            if (gg != g) {   // 30 independent loads, issued back-to-back
                const size_t base = (size_t)(bp * 16 + gg) * 1024 + roff64;
                va[gg] = __hip_atomic_load(&pw[base], __ATOMIC_RELAXED, __HIP_MEMORY_SCOPE_AGENT);
                vb[gg] = __hip_atomic_load(&pw[base + 1], __ATOMIC_RELAXED, __HIP_MEMORY_SCOPE_AGENT);
            }
        }
        {
            unsigned got = 1u << g;
            while (1) {
#pragma unroll
                for (int gg = 0; gg < 16; ++gg) {
                    if (!(got & (1u << gg)) && va[gg] != SENT && vb[gg] != SENT)
                        got |= 1u << gg;
                }
                if (got == 0xFFFFu) break;
                __builtin_amdgcn_s_sleep(1);
#pragma unroll
                for (int gg = 0; gg < 16; ++gg) {
                    if (!(got & (1u << gg))) {
                        const size_t base = (size_t)(bp * 16 + gg) * 1024 + roff64;
                        if (va[gg] == SENT)
                            va[gg] = __hip_atomic_load(&pw[base], __ATOMIC_RELAXED, __HIP_MEMORY_SCOPE_AGENT);
                        if (vb[gg] == SENT)
                            vb[gg] = __hip_atomic_load(&pw[base + 1], __ATOMIC_RELAXED, __HIP_MEMORY_SCOPE_AGENT);
                    }
                }
            }
        }
        // fixed-order sum (deterministic association)
        float u0, u1, u2, u3;
        {
            float a0 = 0, a1 = 0, a2 = 0, a3 = 0;
#pragma unroll
            for (int gg = 0; gg < 16; ++gg) {
                union { unsigned long long u; float2 f; } w0, w1;
                w0.u = va[gg]; w1.u = vb[gg];
                a0 += w0.f.x; a1 += w0.f.y; a2 += w1.f.x; a3 += w1.f.y;
            }
            u0 = tanhf(a0 + bt4.x); u1 = tanhf(a1 + bt4.y);
            u2 = tanhf(a2 + bt4.z); u3 = tanhf(a3 + bt4.w);
            float s1 = (u0 + u1) + (u2 + u3);
            float s2 = (u0 * u0 + u1 * u1) + (u2 * u2 + u3 * u3);
#pragma unroll
            for (int o = 1; o < 64; o <<= 1) {
                s1 += __shfl_xor(s1, o);
                s2 += __shfl_xor(s2, o);
            }
            if ((t & 63) == 0) red2[wid] = make_float2(s1, s2);
        }

        // ---- re-sentinel own region of buffer (s+2)%3 (== buffer of step s-1) ----
        {
            unsigned long long* sw =
                (unsigned long long*)(pP + (size_t)((s + 2) % 3) * PHALF);
            const size_t myb = (size_t)(bp * 16 + g) * 1024 + roff64;
            __hip_atomic_store(&sw[myb], SENT, __ATOMIC_RELAXED, __HIP_MEMORY_SCOPE_AGENT);
            __hip_atomic_store(&sw[myb + 1], SENT, __ATOMIC_RELAXED, __HIP_MEMORY_SCOPE_AGENT);
        }
        __syncthreads();   // red2 ready (also drains stores before next publish)

        // ---- apply LN, stage h_new into hb, write own hsB slice ----
        {
            const float2 A = red2[rB * 2], Bv = red2[rB * 2 + 1];
            const float mean = (A.x + Bv.x) * (1.0f / H_);
            const float var  = (A.y + Bv.y) * (1.0f / H_) - mean * mean;
            const float rs = rsqrtf(var + LN_EPS);
            float4 hn;
            hn.x = (u0 - mean) * rs * gm4.x + be4.x;
            hn.y = (u1 - mean) * rs * gm4.y + be4.y;
            hn.z = (u2 - mean) * rs * gm4.z + be4.z;
            hn.w = (u3 - mean) * rs * gm4.w + be4.w;
            *(float4*)&hb[rB * 516 + jB] = hn;
            if ((jB >> 5) == g) {
                ushort4 o;
                o.x = f2bf(hn.x); o.y = f2bf(hn.y);
                o.z = f2bf(hn.z); o.w = f2bf(hn.w);
                *(ushort4*)&hsB[((size_t)s * B_ + bp * 4 + rB) * H_ + jB] = o;
            }
        }
        __syncthreads();   // hb ready for next phase A
    }
}

// ---------------- output GEMM (bf16 MFMA) ----------------
typedef __attribute__((ext_vector_type(8))) short short8;
typedef __attribute__((ext_vector_type(4))) float f32x4;

__global__ __launch_bounds__(256) void k_out_mfma(
        const unsigned short* __restrict__ hsB, const unsigned short* __restrict__ WoB,
        const float* __restrict__ b_out, float* __restrict__ y) {
    __shared__ unsigned short As[128 * 40];
    __shared__ unsigned short Bs[128 * 40];

    const int v0 = blockIdx.x * 128;
    const int m0 = blockIdx.y * 128;
    const int t = threadIdx.x;
    const int l = t & 63, wv = t >> 6;
    const int wm = wv >> 1, wn = wv & 1;

    f32x4 acc[4][4];
#pragma unroll
    for (int i = 0; i < 4; ++i)
#pragma unroll
        for (int jq = 0; jq < 4; ++jq)
            acc[i][jq] = (f32x4){0.f, 0.f, 0.f, 0.f};

    float bias[4];
#pragma unroll
    for (int ni = 0; ni < 4; ++ni) {
        int v = v0 + wn * 64 + ni * 16 + (l & 15);
        bias[ni] = (v < V_) ? b_out[v] : 0.f;
    }

    for (int k0 = 0; k0 < H_; k0 += 32) {
        __syncthreads();
        for (int c = t; c < 512; c += 256) {
            int row = c >> 2, seg = c & 3;
            *(uint4*)&As[row * 40 + seg * 8] =
                *(const uint4*)&hsB[(size_t)(m0 + row) * H_ + k0 + seg * 8];
            int vr = v0 + row; if (vr > V_ - 1) vr = V_ - 1;
            *(uint4*)&Bs[row * 40 + seg * 8] =
                *(const uint4*)&WoB[(size_t)vr * H_ + k0 + seg * 8];
        }
        __syncthreads();

        short8 af[4], bf[4];
#pragma unroll
        for (int i = 0; i < 4; ++i) {
            af[i] = *(short8*)&As[(wm * 64 + i * 16 + (l & 15)) * 40 + (l >> 4) * 8];
            bf[i] = *(short8*)&Bs[(wn * 64 + i * 16 + (l & 15)) * 40 + (l >> 4) * 8];
        }
#pragma unroll
        for (int mi = 0; mi < 4; ++mi)
#pragma unroll
            for (int ni = 0; ni < 4; ++ni)
                acc[mi][ni] = __builtin_amdgcn_mfma_f32_16x16x32_bf16(
                    af[mi], bf[ni], acc[mi][ni], 0, 0, 0);
    }

#pragma unroll
    for (int mi = 0; mi < 4; ++mi) {
#pragma unroll
        for (int ni = 0; ni < 4; ++ni) {
            int vcol = v0 + wn * 64 + ni * 16 + (l & 15);
            if (vcol < V_) {
#pragma unroll
                for (int p = 0; p < 4; ++p) {
                    int m = m0 + wm * 64 + mi * 16 + (l >> 4) * 4 + p;
                    int s = m >> 5, b = m & 31;
                    y[((size_t)b * S_ + s) * V_ + vcol] = acc[mi][ni][p] + bias[ni];
                }
            }
        }
    }
}

extern "C" void kernel_launch(void* const* d_in, const int* in_sizes, int n_in,
                              void* d_out, int out_size, void* d_ws, size_t ws_size,
                              hipStream_t stream) {
    const int*   x_idx = (const int*)d_in[0];
    const float* emb   = (const float*)d_in[1];
    const float* W_in  = (const float*)d_in[2];
    const float* b_in  = (const float*)d_in[3];
    const float* W_rec = (const float*)d_in[4];
    const float* b_rec = (const float*)d_in[5];
    const float* W_tr  = (const float*)d_in[6];
    const float* b_tr  = (const float*)d_in[7];
    const float* gamma = (const float*)d_in[8];
    const float* beta  = (const float*)d_in[9];
    const float* W_out = (const float*)d_in[10];
    const float* b_out = (const float*)d_in[11];
    float* y  = (float*)d_out;
    float* ws = (float*)d_ws;

    // workspace layout (float units), total ~15.55M floats = 62.2 MB
    float* WinT = ws;                                        // 131072
    float* Xp   = ws + 131072;                               // 8388608
    unsigned short* hsB = (unsigned short*)(ws + 8519680);   // 16384*512 bf16
    unsigned short* WoB = (unsigned short*)(ws + 12713984);  // 8000*512 bf16
    float* pP   = ws + 14761984;                             // 3*PHALF = 786432

    (void)hipFuncSetAttribute((const void*)k_scan_poll,
                              hipFuncAttributeMaxDynamicSharedMemorySize,
                              LDSF * 4);

    dim3 tb(32, 8);
    k_transpose<<<dim3(I_ / 32, H_ / 32), tb, 0, stream>>>(W_in, WinT, H_, I_);

    k_cvt_bf16<<<1024, 256, 0, stream>>>(W_out, WoB, V_ * H_ / 4);

    k_embed_proj<<<(B_ * S_) / 8, 512, 0, stream>>>(x_idx, emb, WinT, b_in, Xp);

    // sentinel-fill all three partial buffers (0xFF bytes == NaN pair per u64)
    hipMemsetAsync(pP, 0xFF, 3 * (size_t)PHALF * sizeof(float), stream);

    k_scan_poll<<<NBLK, 512, LDSF * 4, stream>>>(Xp, W_rec, b_rec, W_tr, b_tr,
                                                 gamma, beta, pP, hsB);

    k_out_mfma<<<dim3((V_ + 127) / 128, (B_ * S_) / 128), 256, 0, stream>>>(
        hsB, WoB, b_out, y);
}

// Round 10
// 3827.633 us; speedup vs baseline: 2.5418x; 2.5418x over previous
//
#include <hip/hip_runtime.h>
#include <hip/hip_bf16.h>

#define B_ 32
#define S_ 512
#define V_ 8000
#define I_ 256
#define H_ 512
#define LN_EPS 1e-5f
#define NSL 16          // j/k-slices of 32
#define NBP 8           // row-groups of 4 rows
#define NBLK 128
#define PHALF (NBLK * 2048)   // one p buffer: 262144 floats

// dynamic-LDS float offsets (total 37288 floats = 149152 B)
#define OFF_WR   0      // [32][516] W_rec slice, j-row k-contig
#define OFF_WT   16512  // [32][516] W_tr^T slice: WtS[kl][j] = W_tr[j][g*32+kl]
#define OFF_HB   33024  // [4][516]  h_prev rows (full H per row)
#define OFF_HTS  35088  // [4][33]   phase-A output h_t (own slice)
#define OFF_RED  35220  // [16][4][32] phase-A k-chunk partials
#define OFF_RED2 37268  // float2[8] LN wave partials
#define OFF_MISC 37284  // [1] int: fast-path flag
#define LDSF     37288

typedef __attribute__((ext_vector_type(4))) float f32x4;
typedef __attribute__((ext_vector_type(8))) short short8;

static __device__ __forceinline__ unsigned short f2bf(float x) {
    __hip_bfloat16 h = __float2bfloat16(x);
    return *reinterpret_cast<unsigned short*>(&h);
}

// ---------------- transpose (W_in only) ----------------
__global__ void k_transpose(const float* __restrict__ in, float* __restrict__ out,
                            int R, int C) {
    __shared__ float tile[32][33];
    int c0 = blockIdx.x * 32, r0 = blockIdx.y * 32;
    int tx = threadIdx.x, ty = threadIdx.y;  // block (32,8)
#pragma unroll
    for (int i = 0; i < 32; i += 8)
        tile[ty + i][tx] = in[(size_t)(r0 + ty + i) * C + (c0 + tx)];
    __syncthreads();
#pragma unroll
    for (int i = 0; i < 32; i += 8)
        out[(size_t)(c0 + ty + i) * R + (r0 + tx)] = tile[tx][ty + i];
}

// ---------------- fp32 -> bf16 convert (W_out) ----------------
__global__ __launch_bounds__(256) void k_cvt_bf16(const float* __restrict__ in,
                                                  unsigned short* __restrict__ out, int n4) {
    for (int i = blockIdx.x * 256 + threadIdx.x; i < n4; i += gridDim.x * 256) {
        float4 v = ((const float4*)in)[i];
        ushort4 o;
        o.x = f2bf(v.x); o.y = f2bf(v.y); o.z = f2bf(v.z); o.w = f2bf(v.w);
        ((ushort4*)out)[i] = o;
    }
}

// ---------------- embed gather + input projection: Xp[m][j], m = s*B+b ----------------
__global__ __launch_bounds__(512) void k_embed_proj(
        const int* __restrict__ x_idx, const float* __restrict__ emb,
        const float* __restrict__ WinT, const float* __restrict__ b_in,
        float* __restrict__ Xp) {
    __shared__ float e[8][I_];
    const int m0 = blockIdx.x * 8;
    const int t = threadIdx.x;
    {
        int r = t >> 6, i4 = (t & 63) * 4;
        int m = m0 + r;
        int s = m >> 5, b = m & 31;
        int idx = x_idx[b * S_ + s];
        *(float4*)&e[r][i4] = *(const float4*)&emb[(size_t)idx * I_ + i4];
    }
    __syncthreads();
    const int j = t;
    float acc[8];
    const float bj = b_in[j];
#pragma unroll
    for (int r = 0; r < 8; ++r) acc[r] = bj;
    for (int i = 0; i < I_; ++i) {
        float w = WinT[(size_t)i * H_ + j];
#pragma unroll
        for (int r = 0; r < 8; ++r) acc[r] += e[r][i] * w;
    }
#pragma unroll
    for (int r = 0; r < 8; ++r)
        Xp[(size_t)(m0 + r) * H_ + j] = acc[r];
}

// ---------------- XCD-local one-barrier distributed scan (v2) ----------------
// 128 blocks x 512 thr; bid = g*8 + bp -> group bp members share bid%8.
// ALL spin loops use agent-scope atomics on monotonic/write-once values
// (R6-proven; cannot hang on unproven coherence). Only the bulk DATA moves
// switch to sc0 (XCD-L2) when the runtime XCC_ID check passes; if sc0 were
// not XCD-coherent the result is wrong data (absmax diagnostic), not a hang.
__global__ __launch_bounds__(512, 2) void k_scan_xcd2(
        const float* __restrict__ Xp,
        const float* __restrict__ W_rec, const float* __restrict__ b_rec,
        const float* __restrict__ W_tr,  const float* __restrict__ b_tr,
        const float* __restrict__ gamma, const float* __restrict__ beta,
        float* __restrict__ pP, unsigned int* __restrict__ flags,
        unsigned int* __restrict__ xccs, unsigned short* __restrict__ hsB) {
    extern __shared__ float sm[];
    float*  WrS  = sm + OFF_WR;
    float*  WtS  = sm + OFF_WT;
    float*  hb   = sm + OFF_HB;
    float*  hts  = sm + OFF_HTS;
    float*  red  = sm + OFF_RED;
    float2* red2 = (float2*)(sm + OFF_RED2);

    const int bid = blockIdx.x;
    const int g = bid >> 3, bp = bid & 7;         // group bp members: bid%8 == bp
    const int t = threadIdx.x;
    const int j = t & 31, kc = t >> 5;            // phase-A role
    const int rB = t >> 7, jB = (t & 127) << 2;   // phase-B / LN role
    const int wid = t >> 6;

    // stage weight slices into LDS once
    for (int idx = t; idx < 32 * 512; idx += 512) {
        int jj = idx >> 9, k = idx & 511;
        WrS[jj * 516 + k] = W_rec[(size_t)(g * 32 + jj) * H_ + k];
    }
    for (int idx = t; idx < 512 * 32; idx += 512) {
        int jj = idx >> 5, kl = idx & 31;
        WtS[kl * 516 + jj] = W_tr[(size_t)jj * H_ + g * 32 + kl];
    }
    const float brj = b_rec[g * 32 + j];
    const float4 bt4 = *(const float4*)&b_tr[jB];
    const float4 gm4 = *(const float4*)&gamma[jB];
    const float4 be4 = *(const float4*)&beta[jB];

    // ---- one-time XCD-mapping check: write-once sentinel, agent scope ----
    unsigned xcc;
    asm volatile("s_getreg_b32 %0, hwreg(HW_REG_XCC_ID)" : "=s"(xcc));
    xcc &= 0xffu;
    if (t == 0)
        __hip_atomic_store(&xccs[bid], xcc, __ATOMIC_RELAXED, __HIP_MEMORY_SCOPE_AGENT);
    {
        int ok = 1;
        if (t < NSL) {
            unsigned v;
            do {
                v = __hip_atomic_load(&xccs[t * 8 + bp],
                                      __ATOMIC_RELAXED, __HIP_MEMORY_SCOPE_AGENT);
                if (v == 0xFFFFFFFFu) __builtin_amdgcn_s_sleep(1);
            } while (v == 0xFFFFFFFFu);
            ok = (v == xcc) ? 1 : 0;
        }
        unsigned long long bal = __ballot(ok);    // wave 0: lanes >=16 vote 1
        if (t == 0)
            ((int*)sm)[OFF_MISC] = (bal == ~0ull) ? 1 : 0;
    }
    __syncthreads();
    const bool fast = ((int*)sm)[OFF_MISC] != 0;

    for (int s = 0; s < S_; ++s) {
        // Xp prefetch for reduce role
        float xv = 0.f;
        if (t < 128) xv = Xp[((size_t)s * B_ + bp * 4 + (t >> 5)) * H_ + g * 32 + (t & 31)];

        // ---- phase A partials: (kc,j) over 32 k for 4 rows ----
        {
            float a0 = 0, a1 = 0, a2 = 0, a3 = 0;
            if (s > 0) {
                const int kbase = kc * 32;
#pragma unroll
                for (int i = 0; i < 8; ++i) {
                    const int k4 = kbase + i * 4;
                    const float4 w4 = *(const float4*)&WrS[j * 516 + k4];
                    const float4 h0 = *(const float4*)&hb[0 * 516 + k4];
                    const float4 h1 = *(const float4*)&hb[1 * 516 + k4];
                    const float4 h2 = *(const float4*)&hb[2 * 516 + k4];
                    const float4 h3 = *(const float4*)&hb[3 * 516 + k4];
                    a0 += h0.x * w4.x + h0.y * w4.y + h0.z * w4.z + h0.w * w4.w;
                    a1 += h1.x * w4.x + h1.y * w4.y + h1.z * w4.z + h1.w * w4.w;
                    a2 += h2.x * w4.x + h2.y * w4.y + h2.z * w4.z + h2.w * w4.w;
                    a3 += h3.x * w4.x + h3.y * w4.y + h3.z * w4.z + h3.w * w4.w;
                }
            }
            red[kc * 128 + 0 * 32 + j] = a0;
            red[kc * 128 + 1 * 32 + j] = a1;
            red[kc * 128 + 2 * 32 + j] = a2;
            red[kc * 128 + 3 * 32 + j] = a3;
        }
        __syncthreads();
        if (t < 128) {
            const int r2 = t >> 5, j2 = t & 31;
            float sum = 0.f;
#pragma unroll
            for (int c = 0; c < 16; ++c) sum += red[c * 128 + r2 * 32 + j2];
            hts[r2 * 33 + j2] = tanhf(sum + xv + brj);
        }
        __syncthreads();

        // ---- phase B: k-slice-g partial of trunk GEMV for ALL j ----
        float4 pa = {0.f, 0.f, 0.f, 0.f};
        {
            const float* hrow = hts + rB * 33;
#pragma unroll 8
            for (int kl = 0; kl < 32; ++kl) {
                const float hv = hrow[kl];
                const float4 w4 = *(const float4*)&WtS[kl * 516 + jB];
                pa.x += hv * w4.x; pa.y += hv * w4.y;
                pa.z += hv * w4.z; pa.w += hv * w4.w;
            }
        }
        // ---- publish own 8KB partial region ----
        {
            float* pdst = pP + (size_t)(s & 1) * PHALF
                        + (size_t)bp * 32768 + g * 2048 + (rB * 512 + jB);
            if (fast) {
                f32x4 pv = {pa.x, pa.y, pa.z, pa.w};
                asm volatile("global_store_dwordx4 %0, %1, off sc0"
                             :: "v"(pdst), "v"(pv) : "memory");
            } else {
                union { float2 f; unsigned long long u; } q0, q1;
                q0.f = make_float2(pa.x, pa.y);
                q1.f = make_float2(pa.z, pa.w);
                __hip_atomic_store((unsigned long long*)pdst, q0.u,
                                   __ATOMIC_RELAXED, __HIP_MEMORY_SCOPE_AGENT);
                __hip_atomic_store((unsigned long long*)pdst + 1, q1.u,
                                   __ATOMIC_RELAXED, __HIP_MEMORY_SCOPE_AGENT);
            }
        }
        // every wave drains its publish stores (incl. inline-asm ones the
        // compiler doesn't track) BEFORE the barrier, so data is in L2/MALL
        // before any flag is released.
        asm volatile("s_waitcnt vmcnt(0)" ::: "memory");
        __syncthreads();

        // ---- single flag barrier, agent scope (R6-proven mechanics) ----
        if (t == 0)
            __hip_atomic_store(&flags[(bp * 16 + g) * 16], (unsigned)(s + 1),
                               __ATOMIC_RELEASE, __HIP_MEMORY_SCOPE_AGENT);
        if (t < NSL)
            while (__hip_atomic_load(&flags[(bp * 16 + t) * 16],
                       __ATOMIC_RELAXED, __HIP_MEMORY_SCOPE_AGENT) < (unsigned)(s + 1))
                __builtin_amdgcn_s_sleep(1);
        __syncthreads();
        __builtin_amdgcn_sched_barrier(0);

        // ---- gather all 16 partials (read-once), fixed-order sum ----
        f32x4 vv[16];
        {
            const float* gbase = pP + (size_t)(s & 1) * PHALF
                               + (size_t)bp * 32768 + (rB * 512 + jB);
            if (fast) {
#pragma unroll
                for (int gg = 0; gg < 16; ++gg)
                    asm volatile("global_load_dwordx4 %0, %1, off sc0"
                                 : "=v"(vv[gg]) : "v"(gbase + gg * 2048) : "memory");
                asm volatile("s_waitcnt vmcnt(0)" ::: "memory");
                __builtin_amdgcn_sched_barrier(0);
            } else {
#pragma unroll
                for (int gg = 0; gg < 16; ++gg) {
                    const unsigned long long* bp64 =
                        (const unsigned long long*)(gbase + gg * 2048);
                    unsigned long long v0 = __hip_atomic_load(bp64,
                        __ATOMIC_RELAXED, __HIP_MEMORY_SCOPE_AGENT);
                    unsigned long long v1 = __hip_atomic_load(bp64 + 1,
                        __ATOMIC_RELAXED, __HIP_MEMORY_SCOPE_AGENT);
                    union { unsigned long long u; float2 f; } w0, w1;
                    w0.u = v0; w1.u = v1;
                    vv[gg] = (f32x4){w0.f.x, w0.f.y, w1.f.x, w1.f.y};
                }
            }
        }
        float u0, u1, u2, u3;
        {
            float a0 = 0, a1 = 0, a2 = 0, a3 = 0;
#pragma unroll
            for (int gg = 0; gg < 16; ++gg) {
                a0 += vv[gg].x; a1 += vv[gg].y; a2 += vv[gg].z; a3 += vv[gg].w;
            }
            u0 = tanhf(a0 + bt4.x); u1 = tanhf(a1 + bt4.y);
            u2 = tanhf(a2 + bt4.z); u3 = tanhf(a3 + bt4.w);
            float s1 = (u0 + u1) + (u2 + u3);
            float s2 = (u0 * u0 + u1 * u1) + (u2 * u2 + u3 * u3);
#pragma unroll
            for (int o = 1; o < 64; o <<= 1) {
                s1 += __shfl_xor(s1, o);
                s2 += __shfl_xor(s2, o);
            }
            if ((t & 63) == 0) red2[wid] = make_float2(s1, s2);
        }
        __syncthreads();

        // ---- apply LN, stage h_new into hb, write own hsB slice ----
        {
            const float2 A = red2[rB * 2], Bv = red2[rB * 2 + 1];
            const float mean = (A.x + Bv.x) * (1.0f / H_);
            const float var  = (A.y + Bv.y) * (1.0f / H_) - mean * mean;
            const float rs = rsqrtf(var + LN_EPS);
            float4 hn;
            hn.x = (u0 - mean) * rs * gm4.x + be4.x;
            hn.y = (u1 - mean) * rs * gm4.y + be4.y;
            hn.z = (u2 - mean) * rs * gm4.z + be4.z;
            hn.w = (u3 - mean) * rs * gm4.w + be4.w;
            *(float4*)&hb[rB * 516 + jB] = hn;
            if ((jB >> 5) == g) {
                ushort4 o;
                o.x = f2bf(hn.x); o.y = f2bf(hn.y);
                o.z = f2bf(hn.z); o.w = f2bf(hn.w);
                *(ushort4*)&hsB[((size_t)s * B_ + bp * 4 + rB) * H_ + jB] = o;
            }
        }
        __syncthreads();                           // hb ready for next phase A
    }
}

// ---------------- output GEMM (bf16 MFMA) ----------------
__global__ __launch_bounds__(256) void k_out_mfma(
        const unsigned short* __restrict__ hsB, const unsigned short* __restrict__ WoB,
        const float* __restrict__ b_out, float* __restrict__ y) {
    __shared__ unsigned short As[128 * 40];
    __shared__ unsigned short Bs[128 * 40];

    const int v0 = blockIdx.x * 128;
    const int m0 = blockIdx.y * 128;
    const int t = threadIdx.x;
    const int l = t & 63, wv = t >> 6;
    const int wm = wv >> 1, wn = wv & 1;

    f32x4 acc[4][4];
#pragma unroll
    for (int i = 0; i < 4; ++i)
#pragma unroll
        for (int jq = 0; jq < 4; ++jq)
            acc[i][jq] = (f32x4){0.f, 0.f, 0.f, 0.f};

    float bias[4];
#pragma unroll
    for (int ni = 0; ni < 4; ++ni) {
        int v = v0 + wn * 64 + ni * 16 + (l & 15);
        bias[ni] = (v < V_) ? b_out[v] : 0.f;
    }

    for (int k0 = 0; k0 < H_; k0 += 32) {
        __syncthreads();
        for (int c = t; c < 512; c += 256) {
            int row = c >> 2, seg = c & 3;
            *(uint4*)&As[row * 40 + seg * 8] =
                *(const uint4*)&hsB[(size_t)(m0 + row) * H_ + k0 + seg * 8];
            int vr = v0 + row; if (vr > V_ - 1) vr = V_ - 1;
            *(uint4*)&Bs[row * 40 + seg * 8] =
                *(const uint4*)&WoB[(size_t)vr * H_ + k0 + seg * 8];
        }
        __syncthreads();

        short8 af[4], bf[4];
#pragma unroll
        for (int i = 0; i < 4; ++i) {
            af[i] = *(short8*)&As[(wm * 64 + i * 16 + (l & 15)) * 40 + (l >> 4) * 8];
            bf[i] = *(short8*)&Bs[(wn * 64 + i * 16 + (l & 15)) * 40 + (l >> 4) * 8];
        }
#pragma unroll
        for (int mi = 0; mi < 4; ++mi)
#pragma unroll
            for (int ni = 0; ni < 4; ++ni)
                acc[mi][ni] = __builtin_amdgcn_mfma_f32_16x16x32_bf16(
                    af[mi], bf[ni], acc[mi][ni], 0, 0, 0);
    }

#pragma unroll
    for (int mi = 0; mi < 4; ++mi) {
#pragma unroll
        for (int ni = 0; ni < 4; ++ni) {
            int vcol = v0 + wn * 64 + ni * 16 + (l & 15);
            if (vcol < V_) {
#pragma unroll
                for (int p = 0; p < 4; ++p) {
                    int m = m0 + wm * 64 + mi * 16 + (l >> 4) * 4 + p;
                    int s = m >> 5, b = m & 31;
                    y[((size_t)b * S_ + s) * V_ + vcol] = acc[mi][ni][p] + bias[ni];
                }
            }
        }
    }
}

extern "C" void kernel_launch(void* const* d_in, const int* in_sizes, int n_in,
                              void* d_out, int out_size, void* d_ws, size_t ws_size,
                              hipStream_t stream) {
    const int*   x_idx = (const int*)d_in[0];
    const float* emb   = (const float*)d_in[1];
    const float* W_in  = (const float*)d_in[2];
    const float* b_in  = (const float*)d_in[3];
    const float* W_rec = (const float*)d_in[4];
    const float* b_rec = (const float*)d_in[5];
    const float* W_tr  = (const float*)d_in[6];
    const float* b_tr  = (const float*)d_in[7];
    const float* gamma = (const float*)d_in[8];
    const float* beta  = (const float*)d_in[9];
    const float* W_out = (const float*)d_in[10];
    const float* b_out = (const float*)d_in[11];
    float* y  = (float*)d_out;
    float* ws = (float*)d_ws;

    // workspace layout (float units)
    float* WinT = ws;                                        // 131072
    float* Xp   = ws + 131072;                               // 8388608
    unsigned short* hsB = (unsigned short*)(ws + 8519680);   // 16384*512 bf16
    unsigned short* WoB = (unsigned short*)(ws + 12713984);  // 8000*512 bf16
    float* pP   = ws + 14761984;                             // 2*PHALF = 524288
    unsigned int* flags = (unsigned int*)(ws + 15286272);    // 2048 u32 (128*16)
    unsigned int* xccs  = (unsigned int*)(ws + 15288320);    // 128 u32

    (void)hipFuncSetAttribute((const void*)k_scan_xcd2,
                              hipFuncAttributeMaxDynamicSharedMemorySize,
                              LDSF * 4);

    dim3 tb(32, 8);
    k_transpose<<<dim3(I_ / 32, H_ / 32), tb, 0, stream>>>(W_in, WinT, H_, I_);

    k_cvt_bf16<<<1024, 256, 0, stream>>>(W_out, WoB, V_ * H_ / 4);

    k_embed_proj<<<(B_ * S_) / 8, 512, 0, stream>>>(x_idx, emb, WinT, b_in, Xp);

    // flags zeroed (poll target >= 1); xccs sentinel 0xFF (write-once poll)
    hipMemsetAsync(flags, 0, 2048 * sizeof(unsigned int), stream);
    hipMemsetAsync(xccs, 0xFF, 128 * sizeof(unsigned int), stream);

    k_scan_xcd2<<<NBLK, 512, LDSF * 4, stream>>>(Xp, W_rec, b_rec, W_tr, b_tr,
                                                 gamma, beta, pP, flags, xccs, hsB);

    k_out_mfma<<<dim3((V_ + 127) / 128, (B_ * S_) / 128), 256, 0, stream>>>(
        hsB, WoB, b_out, y);
}